// Round 6
// baseline (285.194 us; speedup 1.0000x reference)
//
#include <hip/hip_runtime.h>

#define NF 128
#define NBSHIFT 8        // 256 nodes per bucket
#define NBMAX 512        // padded bucket count for scans
#define CHUNK 4096       // edges per multisplit chunk

typedef __attribute__((ext_vector_type(8))) short bf16x8;
typedef __attribute__((ext_vector_type(4))) float f32x4;

__device__ __forceinline__ unsigned short f2bf(float f) {
    unsigned int u = __builtin_bit_cast(unsigned int, f);
    u = (u + 0x7fffu + ((u >> 16) & 1u)) >> 16;
    return (unsigned short)u;
}
__device__ __forceinline__ float bflo(unsigned int u) {
    return __builtin_bit_cast(float, u << 16);
}
__device__ __forceinline__ float bfhi(unsigned int u) {
    return __builtin_bit_cast(float, u & 0xffff0000u);
}

// ================= bucketed CSR build =================

__global__ __launch_bounds__(256) void k_bhist(const int* __restrict__ dst,
                                               int* __restrict__ gbhist, int E, int NB) {
    __shared__ int lh[NBMAX];
    int t = threadIdx.x;
    for (int k = t; k < NBMAX; k += 256) lh[k] = 0;
    __syncthreads();
    int i = blockIdx.x * blockDim.x + t;
    int stride = gridDim.x * blockDim.x;
    for (; i < E; i += stride) atomicAdd(&lh[((unsigned)dst[i]) >> NBSHIFT], 1);
    __syncthreads();
    for (int k = t; k < NB; k += 256)
        if (lh[k]) atomicAdd(&gbhist[k], lh[k]);
}

__global__ __launch_bounds__(256) void k_bscan(const int* __restrict__ gbhist,
                                               int* __restrict__ bbase, int* __restrict__ gcursor,
                                               int NB, int E, int* __restrict__ offsets, int n) {
    __shared__ int sA[NBMAX], sB[NBMAX];
    int t = threadIdx.x;
    for (int k = t; k < NBMAX; k += 256) sA[k] = (k < NB) ? gbhist[k] : 0;
    __syncthreads();
    int* pin = sA;
    int* pout = sB;
    for (int off = 1; off < NBMAX; off <<= 1) {
        for (int k = t; k < NBMAX; k += 256) pout[k] = pin[k] + (k >= off ? pin[k - off] : 0);
        __syncthreads();
        int* tmp = pin; pin = pout; pout = tmp;
    }
    for (int k = t; k < NB; k += 256) {
        int excl = pin[k] - gbhist[k];
        bbase[k] = excl;
        gcursor[k] = excl;
    }
    if (t == 0) {
        bbase[NB] = E;
        offsets[n] = E;
    }
}

// chunked multisplit: stage a 4096-edge chunk in LDS ordered by bucket, then write
// per-bucket runs coalesced with one cursor atomic per (bucket, chunk).
// Edge packed as 32-bit: (dst&255)<<24 | src  (requires n < 2^24).
__global__ __launch_bounds__(256) void k_bucket(const int* __restrict__ src,
                                                const int* __restrict__ dst,
                                                int* __restrict__ gcursor,
                                                unsigned* __restrict__ gpairs, int E) {
    __shared__ int lhist[NBMAX], lbase[NBMAX], lcur[NBMAX], gb[NBMAX];
    __shared__ int sA[NBMAX], sB[NBMAX];
    __shared__ unsigned stage[CHUNK];
    const int t = threadIdx.x;
    const int c0 = blockIdx.x * CHUNK;
    const int cc = min(CHUNK, E - c0);

    for (int k = t; k < NBMAX; k += 256) lhist[k] = 0;
    __syncthreads();

    int ls[16], ld[16];
#pragma unroll
    for (int j = 0; j < 16; ++j) {
        int i = t + j * 256;
        ls[j] = 0; ld[j] = 0;
        if (i < cc) {
            ls[j] = src[c0 + i];
            ld[j] = dst[c0 + i];
            atomicAdd(&lhist[((unsigned)ld[j]) >> NBSHIFT], 1);
        }
    }
    __syncthreads();
    for (int k = t; k < NBMAX; k += 256) sA[k] = lhist[k];
    __syncthreads();
    int* pin = sA;
    int* pout = sB;
    for (int off = 1; off < NBMAX; off <<= 1) {
        for (int k = t; k < NBMAX; k += 256) pout[k] = pin[k] + (k >= off ? pin[k - off] : 0);
        __syncthreads();
        int* tmp = pin; pin = pout; pout = tmp;
    }
    for (int k = t; k < NBMAX; k += 256) {
        int excl = pin[k] - lhist[k];
        lbase[k] = excl;
        lcur[k] = excl;
        int cnt = lhist[k];
        if (cnt > 0) gb[k] = atomicAdd(&gcursor[k], cnt);
    }
    __syncthreads();
#pragma unroll
    for (int j = 0; j < 16; ++j) {
        int i = t + j * 256;
        if (i < cc) {
            int b = ((unsigned)ld[j]) >> NBSHIFT;
            int pos = atomicAdd(&lcur[b], 1);
            stage[pos] = (((unsigned)ld[j] & 255u) << 24) | (unsigned)ls[j];
        }
    }
    __syncthreads();
    for (int idx = t; idx < cc; idx += 256) {
        unsigned p = stage[idx];
        // binary search: largest b with lbase[b] <= idx (lbase sorted, lbase[k]=cc for k>=NB)
        int b = 0;
#pragma unroll
        for (int s = 256; s; s >>= 1) {
            int nb2 = b | s;
            if (lbase[nb2] <= idx) b = nb2;
        }
        gpairs[gb[b] + (idx - lbase[b])] = p;
    }
}

// per-bucket: per-node hist + scan -> offsets/invdeg, scatter esrc within bucket region
__global__ __launch_bounds__(256) void k_bsort(const unsigned* __restrict__ gpairs,
                                               const int* __restrict__ bbase,
                                               int* __restrict__ offsets,
                                               float* __restrict__ invdeg,
                                               int* __restrict__ esrc, int n) {
    __shared__ int lcnt[256], lcur[256], sA[256], sB[256];
    const int b = blockIdx.x;
    const int t = threadIdx.x;
    const int base = bbase[b];
    const int c = bbase[b + 1] - base;
    const int n0 = b << NBSHIFT;

    lcnt[t] = 0;
    __syncthreads();
    for (int i = t; i < c; i += 256) {
        int node = (int)(gpairs[base + i] >> 24);
        atomicAdd(&lcnt[node], 1);
    }
    __syncthreads();
    sA[t] = lcnt[t];
    __syncthreads();
    int* pin = sA;
    int* pout = sB;
    for (int off = 1; off < 256; off <<= 1) {
        pout[t] = pin[t] + (t >= off ? pin[t - off] : 0);
        __syncthreads();
        int* tmp = pin; pin = pout; pout = tmp;
    }
    int excl = pin[t] - lcnt[t];
    lcur[t] = excl;
    int node_g = n0 + t;
    if (node_g < n) {
        offsets[node_g] = base + excl;
        invdeg[node_g] = 1.0f / (float)max(lcnt[t], 1);
    }
    __syncthreads();
    for (int i = t; i < c; i += 256) {
        unsigned p = gpairs[base + i];
        int node = (int)(p >> 24);
        int pos = atomicAdd(&lcur[node], 1);
        esrc[base + pos] = (int)(p & 0x00ffffffu);
    }
}

// ================= conversions =================

__global__ void k_cvt(const float* __restrict__ in, unsigned short* __restrict__ out,
                      long long n8) {
    long long i = (long long)blockIdx.x * blockDim.x + threadIdx.x;
    if (i >= n8) return;
    const float4 a = *reinterpret_cast<const float4*>(in + i * 8);
    const float4 b = *reinterpret_cast<const float4*>(in + i * 8 + 4);
    union { unsigned short s[8]; uint4 u; } o;
    o.s[0] = f2bf(a.x); o.s[1] = f2bf(a.y); o.s[2] = f2bf(a.z); o.s[3] = f2bf(a.w);
    o.s[4] = f2bf(b.x); o.s[5] = f2bf(b.y); o.s[6] = f2bf(b.z); o.s[7] = f2bf(b.w);
    *reinterpret_cast<uint4*>(out + i * 8) = o.u;
}

// Build both Bt[col][k] bf16 (128 x 256) tables in one launch.
__global__ void k_buildBt(const float* __restrict__ Win, const float* __restrict__ Wout,
                          unsigned short* __restrict__ BtIn, unsigned short* __restrict__ BtOut) {
    int bb = blockIdx.x;
    const float* W = (bb < 128) ? Win : Wout;
    unsigned short* Bt = (bb < 128) ? BtIn : BtOut;
    int idx = (bb & 127) * 256 + threadIdx.x;
    int c = idx >> 8;
    int k = idx & 255;
    int p = k >> 7, kk = k & 127;
    Bt[idx] = f2bf(W[((size_t)p * NF + kk) * NF + c]);
}

// ================= gather aggregation (bf16, 4 edges/load) =================
// one wave per dst node; lane = (g = lane>>4: edge slot, q = lane&15: 16B col group).
// One uint4 load fetches 4 full rows per instruction; unroll 16 edges = 4 loads (4KB) in flight.
__global__ __launch_bounds__(256) void k_agg_bf16(const unsigned short* __restrict__ feat,
                                                  const int* __restrict__ esrc,
                                                  const int* __restrict__ offsets,
                                                  const float* __restrict__ invdeg,
                                                  unsigned short* __restrict__ neigh, int n) {
    int wid0 = (int)(((long long)blockIdx.x * blockDim.x + threadIdx.x) >> 6);
    const int wid = __builtin_amdgcn_readfirstlane(wid0);
    if (wid >= n) return;
    const int lane = threadIdx.x & 63;
    const int g = lane >> 4;        // edge slot within quad
    const int q = lane & 15;        // column group: bytes [q*16, q*16+16) = cols 8q..8q+7
    const unsigned qoff = (unsigned)q * 16u;
    const char* fb = (const char*)feat;

    const int beg = offsets[wid];
    const int end = offsets[wid + 1];
    float a0 = 0.f, a1 = 0.f, a2 = 0.f, a3 = 0.f, a4 = 0.f, a5 = 0.f, a6 = 0.f, a7 = 0.f;

    int i = beg;
    for (; i + 16 <= end; i += 16) {
        int e[16];
#pragma unroll
        for (int j = 0; j < 16; ++j) e[j] = esrc[i + j];
#pragma unroll
        for (int u = 0; u < 4; ++u) {
            int es = (g & 2) ? ((g & 1) ? e[u * 4 + 3] : e[u * 4 + 2])
                             : ((g & 1) ? e[u * 4 + 1] : e[u * 4 + 0]);
            uint4 v = *(const uint4*)(fb + (unsigned)es * 256u + qoff);
            a0 += bflo(v.x); a1 += bfhi(v.x);
            a2 += bflo(v.y); a3 += bfhi(v.y);
            a4 += bflo(v.z); a5 += bfhi(v.z);
            a6 += bflo(v.w); a7 += bfhi(v.w);
        }
    }
    for (; i + 4 <= end; i += 4) {
        int e0 = esrc[i + 0], e1 = esrc[i + 1], e2 = esrc[i + 2], e3 = esrc[i + 3];
        int es = (g & 2) ? ((g & 1) ? e3 : e2) : ((g & 1) ? e1 : e0);
        uint4 v = *(const uint4*)(fb + (unsigned)es * 256u + qoff);
        a0 += bflo(v.x); a1 += bfhi(v.x);
        a2 += bflo(v.y); a3 += bfhi(v.y);
        a4 += bflo(v.z); a5 += bfhi(v.z);
        a6 += bflo(v.w); a7 += bfhi(v.w);
    }
    if (i < end) {
        int r = end - i;  // 1..3
        if (g < r) {
            int es = esrc[i + g];
            uint4 v = *(const uint4*)(fb + (unsigned)es * 256u + qoff);
            a0 += bflo(v.x); a1 += bfhi(v.x);
            a2 += bflo(v.y); a3 += bfhi(v.y);
            a4 += bflo(v.z); a5 += bfhi(v.z);
            a6 += bflo(v.w); a7 += bfhi(v.w);
        }
    }
    // reduce across the 4 edge slots (lanes q, 16+q, 32+q, 48+q)
    a0 += __shfl_xor(a0, 16); a1 += __shfl_xor(a1, 16);
    a2 += __shfl_xor(a2, 16); a3 += __shfl_xor(a3, 16);
    a4 += __shfl_xor(a4, 16); a5 += __shfl_xor(a5, 16);
    a6 += __shfl_xor(a6, 16); a7 += __shfl_xor(a7, 16);
    a0 += __shfl_xor(a0, 32); a1 += __shfl_xor(a1, 32);
    a2 += __shfl_xor(a2, 32); a3 += __shfl_xor(a3, 32);
    a4 += __shfl_xor(a4, 32); a5 += __shfl_xor(a5, 32);
    a6 += __shfl_xor(a6, 32); a7 += __shfl_xor(a7, 32);

    const float sc = invdeg[wid];
    a0 *= sc; a1 *= sc; a2 *= sc; a3 *= sc;
    a4 *= sc; a5 *= sc; a6 *= sc; a7 *= sc;
    unsigned p0, p1, p2, p3;
    asm("v_cvt_pk_bf16_f32 %0, %1, %2" : "=v"(p0) : "v"(a0), "v"(a1));
    asm("v_cvt_pk_bf16_f32 %0, %1, %2" : "=v"(p1) : "v"(a2), "v"(a3));
    asm("v_cvt_pk_bf16_f32 %0, %1, %2" : "=v"(p2) : "v"(a4), "v"(a5));
    asm("v_cvt_pk_bf16_f32 %0, %1, %2" : "=v"(p3) : "v"(a6), "v"(a7));
    if (g == 0) {
        uint4 o; o.x = p0; o.y = p1; o.z = p2; o.w = p3;
        *(uint4*)((char*)neigh + (size_t)wid * 256 + qoff) = o;
    }
}

// fallback fp32-source aggregate (only used if ws too small for xb)
__global__ __launch_bounds__(256) void k_agg_f32(const float* __restrict__ feat,
                                                 const int* __restrict__ esrc,
                                                 const int* __restrict__ offsets,
                                                 const float* __restrict__ invdeg,
                                                 unsigned short* __restrict__ neigh, int n) {
    int wid0 = (int)(((long long)blockIdx.x * blockDim.x + threadIdx.x) >> 6);
    const int wid = __builtin_amdgcn_readfirstlane(wid0);
    if (wid >= n) return;
    int lane = threadIdx.x & 63;
    int beg = offsets[wid], end = offsets[wid + 1];
    float a0 = 0.f, a1 = 0.f;
    for (int i = beg; i < end; ++i) {
        int s0 = esrc[i];
        float2 v0 = *(const float2*)(feat + (size_t)s0 * NF + lane * 2);
        a0 += v0.x; a1 += v0.y;
    }
    float sc = invdeg[wid];
    unsigned pk;
    float ca = a0 * sc, cb = a1 * sc;
    asm("v_cvt_pk_bf16_f32 %0, %1, %2" : "=v"(pk) : "v"(ca), "v"(cb));
    *(unsigned*)(neigh + (size_t)wid * NF + lane * 2) = pk;
}

// ================= MFMA GEMM: out = act(A1 @ W[0] + A2 @ W[1]) =================
// K=256 (k<128 from A1, k>=128 from A2=neigh). Bt[col][k] bf16.
// 256 threads = 4 waves; wave owns 32 rows x 128 cols (2 A-frags share each B-frag).
template <bool RELU, bool A1BF16, bool OUTBF16>
__global__ __launch_bounds__(256) void k_gemm_mfma(const void* __restrict__ A1v,
                                                   const unsigned short* __restrict__ A2,
                                                   const unsigned short* __restrict__ Bt,
                                                   void* __restrict__ outv, int nrows) {
    const int tid = threadIdx.x;
    const int wave = tid >> 6;
    const int lane = tid & 63;
    const int l15 = lane & 15;
    const int lk = lane >> 4;  // k-group 0..3
    const int rbase = blockIdx.x * 128 + wave * 32;

    f32x4 acc0[8], acc1[8];
#pragma unroll
    for (int t = 0; t < 8; ++t) { acc0[t] = (f32x4)0.0f; acc1[t] = (f32x4)0.0f; }

    const int ar0 = rbase + l15;
    const int ar1 = rbase + 16 + l15;
    const bool ok0 = ar0 < nrows;
    const bool ok1 = ar1 < nrows;

    for (int kc = 0; kc < 8; ++kc) {
        bf16x8 a0 = (bf16x8)(short)0, a1 = (bf16x8)(short)0;
        if (kc < 4) {
            if (A1BF16) {
                const unsigned short* A1 = (const unsigned short*)A1v;
                if (ok0) a0 = *(const bf16x8*)(A1 + (size_t)ar0 * NF + kc * 32 + lk * 8);
                if (ok1) a1 = *(const bf16x8*)(A1 + (size_t)ar1 * NF + kc * 32 + lk * 8);
            } else {
                const float* A1 = (const float*)A1v;
                if (ok0) {
                    const float* p = A1 + (size_t)ar0 * NF + kc * 32 + lk * 8;
                    float4 u = *(const float4*)p;
                    float4 v = *(const float4*)(p + 4);
                    a0[0] = (short)f2bf(u.x); a0[1] = (short)f2bf(u.y);
                    a0[2] = (short)f2bf(u.z); a0[3] = (short)f2bf(u.w);
                    a0[4] = (short)f2bf(v.x); a0[5] = (short)f2bf(v.y);
                    a0[6] = (short)f2bf(v.z); a0[7] = (short)f2bf(v.w);
                }
                if (ok1) {
                    const float* p = A1 + (size_t)ar1 * NF + kc * 32 + lk * 8;
                    float4 u = *(const float4*)p;
                    float4 v = *(const float4*)(p + 4);
                    a1[0] = (short)f2bf(u.x); a1[1] = (short)f2bf(u.y);
                    a1[2] = (short)f2bf(u.z); a1[3] = (short)f2bf(u.w);
                    a1[4] = (short)f2bf(v.x); a1[5] = (short)f2bf(v.y);
                    a1[6] = (short)f2bf(v.z); a1[7] = (short)f2bf(v.w);
                }
            }
        } else {
            if (ok0) a0 = *(const bf16x8*)(A2 + (size_t)ar0 * NF + (kc - 4) * 32 + lk * 8);
            if (ok1) a1 = *(const bf16x8*)(A2 + (size_t)ar1 * NF + (kc - 4) * 32 + lk * 8);
        }
#pragma unroll
        for (int t = 0; t < 8; ++t) {
            bf16x8 b = *(const bf16x8*)(Bt + (size_t)(t * 16 + l15) * 256 + kc * 32 + lk * 8);
            acc0[t] = __builtin_amdgcn_mfma_f32_16x16x32_bf16(a0, b, acc0[t], 0, 0, 0);
            acc1[t] = __builtin_amdgcn_mfma_f32_16x16x32_bf16(a1, b, acc1[t], 0, 0, 0);
        }
    }

#pragma unroll
    for (int f = 0; f < 2; ++f) {
        const int orow0 = rbase + f * 16 + lk * 4;
#pragma unroll
        for (int r = 0; r < 4; ++r) {
            int orow = orow0 + r;
            if (orow >= nrows) continue;
#pragma unroll
            for (int t = 0; t < 8; ++t) {
                float v = f ? acc1[t][r] : acc0[t][r];
                if (RELU) v = fmaxf(v, 0.f);
                if (OUTBF16)
                    ((unsigned short*)outv)[(size_t)orow * NF + t * 16 + l15] = f2bf(v);
                else
                    ((float*)outv)[(size_t)orow * NF + t * 16 + l15] = v;
            }
        }
    }
}

extern "C" void kernel_launch(void* const* d_in, const int* in_sizes, int n_in,
                              void* d_out, int out_size, void* d_ws, size_t ws_size,
                              hipStream_t stream) {
    const float* x = (const float*)d_in[0];
    const float* W_in = (const float*)d_in[1];
    const float* W_out = (const float*)d_in[2];
    const int* src = (const int*)d_in[3];
    const int* dst = (const int*)d_in[4];

    const int n = in_sizes[0] / NF;  // 100000  (must stay < 2^24 for packed CSR)
    const int E = in_sizes[3];       // 1600000
    float* outp = (float*)d_out;

    const int NB = (n + 255) >> NBSHIFT;
    const int nchunks = (E + CHUNK - 1) / CHUNK;

    // workspace carve
    char* ws = (char*)d_ws;
    size_t off = 0;
    auto take = [&](size_t bytes) {
        void* p = ws + off;
        off = (off + bytes + 511) & ~(size_t)511;
        return p;
    };
    int* gbhist = (int*)take((size_t)NB * 4);
    int* bbase = (int*)take((size_t)(NB + 1) * 4);
    int* gcursor = (int*)take((size_t)NB * 4);
    int* offsets = (int*)take((size_t)(n + 1) * 4);
    float* invdeg = (float*)take((size_t)n * 4);
    unsigned short* BtIn = (unsigned short*)take(128 * 256 * 2);
    unsigned short* BtOut = (unsigned short*)take(128 * 256 * 2);
    unsigned* gpairs = (unsigned*)take((size_t)E * 4);
    int* esrc = (int*)take((size_t)E * 4);
    unsigned short* hb = (unsigned short*)take((size_t)n * NF * 2);
    unsigned short* neigh = (unsigned short*)take((size_t)n * NF * 2);
    bool use_xb = (ws_size >= off + (size_t)n * NF * 2);
    unsigned short* xb = use_xb ? (unsigned short*)take((size_t)n * NF * 2) : nullptr;

    // ---- CSR build ----
    hipMemsetAsync(gbhist, 0, (size_t)NB * 4, stream);
    k_bhist<<<512, 256, 0, stream>>>(dst, gbhist, E, NB);
    k_bscan<<<1, 256, 0, stream>>>(gbhist, bbase, gcursor, NB, E, offsets, n);
    k_bucket<<<nchunks, 256, 0, stream>>>(src, dst, gcursor, gpairs, E);
    k_bsort<<<NB, 256, 0, stream>>>(gpairs, bbase, offsets, invdeg, esrc, n);

    // ---- weights -> Bt bf16 (both in one launch) ----
    k_buildBt<<<256, 256, 0, stream>>>(W_in, W_out, BtIn, BtOut);

    if (use_xb) {
        long long n8 = (long long)n * NF / 8;
        k_cvt<<<(unsigned)((n8 + 255) / 256), 256, 0, stream>>>(x, xb, n8);
    }

    const int aggBlocks = (n + 3) / 4;
    const int gemmBlocks = (n + 127) / 128;

    // ---- layer 0 ----
    if (use_xb) {
        k_agg_bf16<<<aggBlocks, 256, 0, stream>>>(xb, esrc, offsets, invdeg, neigh, n);
        k_gemm_mfma<true, true, true>
            <<<gemmBlocks, 256, 0, stream>>>(xb, neigh, BtIn, hb, n);
    } else {
        k_agg_f32<<<aggBlocks, 256, 0, stream>>>(x, esrc, offsets, invdeg, neigh, n);
        k_gemm_mfma<true, false, true>
            <<<gemmBlocks, 256, 0, stream>>>(x, neigh, BtIn, hb, n);
    }

    // ---- layer 1 ----
    k_agg_bf16<<<aggBlocks, 256, 0, stream>>>(hb, esrc, offsets, invdeg, neigh, n);
    k_gemm_mfma<false, true, false>
        <<<gemmBlocks, 256, 0, stream>>>(hb, neigh, BtOut, outp, n);
}